// Round 1
// baseline (912.546 us; speedup 1.0000x reference)
//
#include <hip/hip_runtime.h>
#include <stdint.h>

#define DD 128
#define EPS 1e-5f

static __device__ __forceinline__ void fma4(float4& a, float s, const float4& w){
  a.x = fmaf(s, w.x, a.x); a.y = fmaf(s, w.y, a.y);
  a.z = fmaf(s, w.z, a.z); a.w = fmaf(s, w.w, a.w);
}

// ---------------- degree histogram (also CSR counts) ----------------
__global__ __launch_bounds__(256) void degree_kernel(const int* __restrict__ src, const int* __restrict__ dst,
                                                     int* __restrict__ deg_out, int* __restrict__ deg_in, int ne){
  int e = blockIdx.x*256 + threadIdx.x;
  if (e < ne){
    atomicAdd(&deg_out[src[e]], 1);
    atomicAdd(&deg_in[dst[e]], 1);
  }
}

__global__ __launch_bounds__(256) void norm_kernel(const int* __restrict__ deg_out, const int* __restrict__ deg_in,
                                                   float* __restrict__ ns, float* __restrict__ nd, int n){
  int i = blockIdx.x*256 + threadIdx.x;
  if (i < n){
    int dout = deg_out[i] > 1 ? deg_out[i] : 1;
    int din  = deg_in[i]  > 1 ? deg_in[i]  : 1;
    ns[i] = rsqrtf((float)dout);
    nd[i] = rsqrtf((float)din);
  }
}

// ---------------- single-block prefix sum over deg_in -> rowptr ----------------
__global__ __launch_bounds__(1024) void scan_kernel(const int* __restrict__ counts, int* __restrict__ rowptr, int n){
  __shared__ int wsum[16];
  __shared__ int sbase, snext;
  int t = threadIdx.x, lane = t & 63, w = t >> 6;
  if (t == 0) sbase = 0;
  __syncthreads();
  int ntiles = (n + 1023) >> 10;
  for (int tile = 0; tile < ntiles; tile++){
    int i = (tile << 10) + t;
    int v = (i < n) ? counts[i] : 0;
    int x = v;
    #pragma unroll
    for (int off = 1; off < 64; off <<= 1){
      int u = __shfl_up(x, off);
      if (lane >= off) x += u;
    }
    if (lane == 63) wsum[w] = x;
    __syncthreads();
    if (t == 0){
      int acc = 0;
      #pragma unroll
      for (int k2 = 0; k2 < 16; k2++){ int s = wsum[k2]; wsum[k2] = acc; acc += s; }
      snext = sbase + acc;
    }
    __syncthreads();
    int excl = sbase + wsum[w] + x - v;
    if (i < n) rowptr[i] = excl;
    if (i == n - 1) rowptr[n] = excl + v;
    __syncthreads();
    if (t == 0) sbase = snext;
    __syncthreads();
  }
}

// ---------------- CSR fill (edge id -> slot under its dst) ----------------
__global__ __launch_bounds__(256) void fill_kernel(const int* __restrict__ src, const int* __restrict__ dst,
                                                   const int* __restrict__ rowptr, int* __restrict__ cursor,
                                                   int* __restrict__ csr_src, int ne){
  int e = blockIdx.x*256 + threadIdx.x;
  if (e < ne){
    int d = dst[e];
    int pos = rowptr[d] + atomicAdd(&cursor[d], 1);
    csr_src[pos] = src[e];
  }
}

// ---------------- GEMM: hout = f(hin) * nsrc @ W ----------------
// f = identity (layer0) or BN-scale/shift + relu (fused from previous layer)
__global__ __launch_bounds__(256) void gemm_kernel(
    const float* __restrict__ hin, const float* __restrict__ W,
    const float* __restrict__ nsrc, const float* __restrict__ ss, int has_ss,
    float* __restrict__ hout, int nrows)
{
  __shared__ __align__(16) float lw[DD*DD];    // 64 KB
  __shared__ __align__(16) float ht[DD*36];    // 18 KB  [k][row] transposed tile, pad 36
  __shared__ float lsc[DD], lsh[DD];
  int t = threadIdx.x;
  {
    const float4* W4 = (const float4*)W;
    float4* lw4 = (float4*)lw;
    #pragma unroll
    for (int i = 0; i < 16; i++) lw4[i*256 + t] = W4[i*256 + t];
  }
  if (t < DD){
    lsc[t] = has_ss ? ss[t]      : 1.0f;
    lsh[t] = has_ss ? ss[DD + t] : 0.0f;
  }
  __syncthreads();   // lsc/lsh visible to staging reads below

  int base = blockIdx.x * 32;
  #pragma unroll
  for (int i = 0; i < 16; i++){
    int idx = i*256 + t;          // 0..4095
    int r = idx >> 7, cc = idx & 127;
    int row = base + r;
    float v = 0.f;
    if (row < nrows){
      v = hin[(size_t)row*DD + cc];
      v = fmaf(v, lsc[cc], lsh[cc]);
      if (has_ss) v = fmaxf(v, 0.f);
      v *= nsrc[row];
    }
    ht[cc*36 + r] = v;
  }
  __syncthreads();

  int j = t & 31, g = t >> 5;     // j: col group (cols 4j..4j+3), g: row group (rows g*4..g*4+3)
  float4 a0 = {0,0,0,0}, a1 = {0,0,0,0}, a2 = {0,0,0,0}, a3 = {0,0,0,0};
  #pragma unroll 8
  for (int k = 0; k < DD; k++){
    float4 hv = *(const float4*)&ht[k*36 + g*4];
    float4 wv = *(const float4*)&lw[k*DD + j*4];
    fma4(a0, hv.x, wv); fma4(a1, hv.y, wv); fma4(a2, hv.z, wv); fma4(a3, hv.w, wv);
  }
  int r0 = base + g*4;
  if (r0 + 0 < nrows) *(float4*)&hout[(size_t)(r0+0)*DD + j*4] = a0;
  if (r0 + 1 < nrows) *(float4*)&hout[(size_t)(r0+1)*DD + j*4] = a1;
  if (r0 + 2 < nrows) *(float4*)&hout[(size_t)(r0+2)*DD + j*4] = a2;
  if (r0 + 3 < nrows) *(float4*)&hout[(size_t)(r0+3)*DD + j*4] = a3;
}

// ---------------- CSR aggregate + epilogue (+ optional BN stats) ----------------
// one wave per node: 64 lanes x float2 = 128 cols
__global__ __launch_bounds__(256) void agg_kernel(
    const float* __restrict__ h2, const int* __restrict__ rowptr,
    const int* __restrict__ csr_src, const float* __restrict__ ndst,
    const float* __restrict__ bias, float* __restrict__ hout,
    float* __restrict__ colsum, float* __restrict__ colsq,
    int do_stats, int nnodes)
{
  __shared__ float red[256];
  int t = threadIdx.x;
  int lane = t & 63, w = t >> 6;
  int slot = blockIdx.x*4 + w, nslots = gridDim.x*4;
  int c = lane*2;
  float b0 = bias[c], b1 = bias[c+1];
  float s0 = 0, s1 = 0, q0 = 0, q1 = 0;
  for (int node = slot; node < nnodes; node += nslots){
    int beg = rowptr[node], end = rowptr[node+1];
    float a0 = 0.f, a1 = 0.f;
    for (int i = beg; i < end; i++){
      int sidx = csr_src[i];
      float2 hv = *(const float2*)&h2[(size_t)sidx*DD + c];
      a0 += hv.x; a1 += hv.y;
    }
    float ndv = ndst[node];
    float v0 = fmaf(a0, ndv, b0), v1 = fmaf(a1, ndv, b1);
    float2 vv; vv.x = v0; vv.y = v1;
    *(float2*)&hout[(size_t)node*DD + c] = vv;
    s0 += v0; s1 += v1; q0 += v0*v0; q1 += v1*v1;
  }
  if (do_stats){
    red[t] = s0; __syncthreads();
    if (t < 64) atomicAdd(&colsum[t*2],   red[t] + red[t+64] + red[t+128] + red[t+192]);
    __syncthreads();
    red[t] = s1; __syncthreads();
    if (t < 64) atomicAdd(&colsum[t*2+1], red[t] + red[t+64] + red[t+128] + red[t+192]);
    __syncthreads();
    red[t] = q0; __syncthreads();
    if (t < 64) atomicAdd(&colsq[t*2],    red[t] + red[t+64] + red[t+128] + red[t+192]);
    __syncthreads();
    red[t] = q1; __syncthreads();
    if (t < 64) atomicAdd(&colsq[t*2+1],  red[t] + red[t+64] + red[t+128] + red[t+192]);
  }
}

// ---------------- BN finalize: per-col scale/shift ----------------
__global__ __launch_bounds__(DD) void bnfin_kernel(const float* __restrict__ colsum, const float* __restrict__ colsq,
                                                   const float* __restrict__ gamma, const float* __restrict__ beta,
                                                   float* __restrict__ ss, int n){
  int c = threadIdx.x;
  float invn = 1.0f / (float)n;
  float mean = colsum[c] * invn;
  float var  = colsq[c] * invn - mean*mean;
  var = fmaxf(var, 0.f);
  float sc = gamma[c] * rsqrtf(var + EPS);
  ss[c] = sc;
  ss[DD + c] = beta[c] - mean*sc;
}

extern "C" void kernel_launch(void* const* d_in, const int* in_sizes, int n_in,
                              void* d_out, int out_size, void* d_ws, size_t ws_size,
                              hipStream_t stream) {
  const float* feat   = (const float*)d_in[0];
  const int*   src    = (const int*)d_in[1];
  const int*   dst    = (const int*)d_in[2];
  const float* Ws     = (const float*)d_in[3];
  const float* bs     = (const float*)d_in[4];
  const float* gammas = (const float*)d_in[5];
  const float* betas  = (const float*)d_in[6];
  float* out = (float*)d_out;

  int n  = in_sizes[0] / DD;   // 50000
  int ne = in_sizes[1];        // 800000

  char* p = (char*)d_ws;
  int* deg_out = (int*)p; p += (size_t)n*sizeof(int);
  int* deg_in  = (int*)p; p += (size_t)n*sizeof(int);
  int* rowptr  = (int*)p; p += (size_t)(n+1)*sizeof(int);
  int* cursor  = (int*)p; p += (size_t)n*sizeof(int);
  int* csr_src = (int*)p; p += (size_t)ne*sizeof(int);
  float* ns      = (float*)p; p += (size_t)n*sizeof(float);
  float* nd      = (float*)p; p += (size_t)n*sizeof(float);
  float* colsum  = (float*)p; p += DD*sizeof(float);
  float* colsq   = (float*)p; p += DD*sizeof(float);
  float* scsh    = (float*)p; p += 2*DD*sizeof(float);
  p = (char*)(((uintptr_t)p + 255) & ~(uintptr_t)255);
  float* B0 = (float*)p; p += (size_t)n*DD*sizeof(float);

  // degrees + norms + CSR build (recomputed every call; ws is poisoned)
  hipMemsetAsync(deg_out, 0, 2*(size_t)n*sizeof(int), stream);   // deg_out,deg_in contiguous
  degree_kernel<<<(ne+255)/256, 256, 0, stream>>>(src, dst, deg_out, deg_in, ne);
  norm_kernel<<<(n+255)/256, 256, 0, stream>>>(deg_out, deg_in, ns, nd, n);
  scan_kernel<<<1, 1024, 0, stream>>>(deg_in, rowptr, n);
  hipMemsetAsync(cursor, 0, (size_t)n*sizeof(int), stream);
  fill_kernel<<<(ne+255)/256, 256, 0, stream>>>(src, dst, rowptr, cursor, csr_src, ne);

  for (int L = 0; L < 3; L++){
    const float* hin = (L == 0) ? feat : out;
    gemm_kernel<<<(n+31)/32, 256, 0, stream>>>(hin, Ws + (size_t)L*DD*DD, ns, scsh, (L > 0) ? 1 : 0, B0, n);
    int do_stats = (L < 2) ? 1 : 0;
    if (do_stats) hipMemsetAsync(colsum, 0, 2*DD*sizeof(float), stream);  // colsum,colsq contiguous
    agg_kernel<<<2048, 256, 0, stream>>>(B0, rowptr, csr_src, nd, bs + (size_t)L*DD, out,
                                         colsum, colsq, do_stats, n);
    if (do_stats) bnfin_kernel<<<1, DD, 0, stream>>>(colsum, colsq, gammas + (size_t)L*DD,
                                                     betas + (size_t)L*DD, scsh, n);
  }
}

// Round 9
// 831.876 us; speedup vs baseline: 1.0970x; 1.0970x over previous
//
#include <hip/hip_runtime.h>
#include <stdint.h>

#define DD 128
#define EPS 1e-5f

static __device__ __forceinline__ void fma4(float4& a, float s, const float4& w){
  a.x = fmaf(s, w.x, a.x); a.y = fmaf(s, w.y, a.y);
  a.z = fmaf(s, w.z, a.z); a.w = fmaf(s, w.w, a.w);
}

// ---------------- degree histogram (also CSR counts) ----------------
__global__ __launch_bounds__(256) void degree_kernel(const int* __restrict__ src, const int* __restrict__ dst,
                                                     int* __restrict__ deg_out, int* __restrict__ deg_in, int ne){
  int e = blockIdx.x*256 + threadIdx.x;
  if (e < ne){
    atomicAdd(&deg_out[src[e]], 1);
    atomicAdd(&deg_in[dst[e]], 1);
  }
}

__global__ __launch_bounds__(256) void norm_kernel(const int* __restrict__ deg_out, const int* __restrict__ deg_in,
                                                   float* __restrict__ ns, float* __restrict__ nd, int n){
  int i = blockIdx.x*256 + threadIdx.x;
  if (i < n){
    int dout = deg_out[i] > 1 ? deg_out[i] : 1;
    int din  = deg_in[i]  > 1 ? deg_in[i]  : 1;
    ns[i] = rsqrtf((float)dout);
    nd[i] = rsqrtf((float)din);
  }
}

// ---------------- single-block prefix sum over deg_in -> rowptr ----------------
__global__ __launch_bounds__(1024) void scan_kernel(const int* __restrict__ counts, int* __restrict__ rowptr, int n){
  __shared__ int wsum[16];
  __shared__ int sbase, snext;
  int t = threadIdx.x, lane = t & 63, w = t >> 6;
  if (t == 0) sbase = 0;
  __syncthreads();
  int ntiles = (n + 1023) >> 10;
  for (int tile = 0; tile < ntiles; tile++){
    int i = (tile << 10) + t;
    int v = (i < n) ? counts[i] : 0;
    int x = v;
    #pragma unroll
    for (int off = 1; off < 64; off <<= 1){
      int u = __shfl_up(x, off);
      if (lane >= off) x += u;
    }
    if (lane == 63) wsum[w] = x;
    __syncthreads();
    if (t == 0){
      int acc = 0;
      #pragma unroll
      for (int k2 = 0; k2 < 16; k2++){ int s = wsum[k2]; wsum[k2] = acc; acc += s; }
      snext = sbase + acc;
    }
    __syncthreads();
    int excl = sbase + wsum[w] + x - v;
    if (i < n) rowptr[i] = excl;
    if (i == n - 1) rowptr[n] = excl + v;
    __syncthreads();
    if (t == 0) sbase = snext;
    __syncthreads();
  }
}

// ---------------- CSR fill (edge id -> slot under its dst) ----------------
__global__ __launch_bounds__(256) void fill_kernel(const int* __restrict__ src, const int* __restrict__ dst,
                                                   const int* __restrict__ rowptr, int* __restrict__ cursor,
                                                   int* __restrict__ csr_src, int ne){
  int e = blockIdx.x*256 + threadIdx.x;
  if (e < ne){
    int d = dst[e];
    int pos = rowptr[d] + atomicAdd(&cursor[d], 1);
    csr_src[pos] = src[e];
  }
}

// ---------------- GEMM: hout = f(hin) * nsrc @ W ----------------
// f = identity (layer0) or BN-scale/shift + relu (fused from previous layer)
__global__ __launch_bounds__(256) void gemm_kernel(
    const float* __restrict__ hin, const float* __restrict__ W,
    const float* __restrict__ nsrc, const float* __restrict__ ss, int has_ss,
    float* __restrict__ hout, int nrows)
{
  __shared__ __align__(16) float lw[DD*DD];    // 64 KB
  __shared__ __align__(16) float ht[DD*36];    // 18 KB  [k][row] transposed tile, pad 36
  __shared__ float lsc[DD], lsh[DD];
  int t = threadIdx.x;
  {
    const float4* W4 = (const float4*)W;
    float4* lw4 = (float4*)lw;
    #pragma unroll
    for (int i = 0; i < 16; i++) lw4[i*256 + t] = W4[i*256 + t];
  }
  if (t < DD){
    lsc[t] = has_ss ? ss[t]      : 1.0f;
    lsh[t] = has_ss ? ss[DD + t] : 0.0f;
  }
  __syncthreads();   // lsc/lsh visible to staging reads below

  int base = blockIdx.x * 32;
  #pragma unroll
  for (int i = 0; i < 16; i++){
    int idx = i*256 + t;          // 0..4095
    int r = idx >> 7, cc = idx & 127;
    int row = base + r;
    float v = 0.f;
    if (row < nrows){
      v = hin[(size_t)row*DD + cc];
      v = fmaf(v, lsc[cc], lsh[cc]);
      if (has_ss) v = fmaxf(v, 0.f);
      v *= nsrc[row];
    }
    ht[cc*36 + r] = v;
  }
  __syncthreads();

  int j = t & 31, g = t >> 5;     // j: col group (cols 4j..4j+3), g: row group (rows g*4..g*4+3)
  float4 a0 = {0,0,0,0}, a1 = {0,0,0,0}, a2 = {0,0,0,0}, a3 = {0,0,0,0};
  #pragma unroll 8
  for (int k = 0; k < DD; k++){
    float4 hv = *(const float4*)&ht[k*36 + g*4];
    float4 wv = *(const float4*)&lw[k*DD + j*4];
    fma4(a0, hv.x, wv); fma4(a1, hv.y, wv); fma4(a2, hv.z, wv); fma4(a3, hv.w, wv);
  }
  int r0 = base + g*4;
  if (r0 + 0 < nrows) *(float4*)&hout[(size_t)(r0+0)*DD + j*4] = a0;
  if (r0 + 1 < nrows) *(float4*)&hout[(size_t)(r0+1)*DD + j*4] = a1;
  if (r0 + 2 < nrows) *(float4*)&hout[(size_t)(r0+2)*DD + j*4] = a2;
  if (r0 + 3 < nrows) *(float4*)&hout[(size_t)(r0+3)*DD + j*4] = a3;
}

// ---------------- CSR aggregate + epilogue (+ optional BN stats) ----------------
// one wave per node: 64 lanes x float2 = 128 cols.
// vs round-1: indices bulk-loaded coalesced + shfl-broadcast, 8-deep unrolled
// gathers (8 independent 512B-row loads in flight).
__global__ __launch_bounds__(256) void agg_kernel(
    const float* __restrict__ h2, const int* __restrict__ rowptr,
    const int* __restrict__ csr_src, const float* __restrict__ ndst,
    const float* __restrict__ bias, float* __restrict__ hout,
    float* __restrict__ colsum, float* __restrict__ colsq,
    int do_stats, int nnodes)
{
  __shared__ float red[256];
  int t = threadIdx.x;
  int lane = t & 63, w = t >> 6;
  int slot = blockIdx.x*4 + w, nslots = gridDim.x*4;
  int c = lane*2;
  float b0 = bias[c], b1 = bias[c+1];
  float s0 = 0, s1 = 0, q0 = 0, q1 = 0;
  for (int node = slot; node < nnodes; node += nslots){
    int beg = rowptr[node], end = rowptr[node+1];
    int cnt = end - beg;
    float a0 = 0.f, a1 = 0.f;
    for (int bse = 0; bse < cnt; bse += 64){
      int m = cnt - bse; if (m > 64) m = 64;
      int myidx = (bse + lane < cnt) ? csr_src[beg + bse + lane] : 0;
      int j = 0;
      for (; j + 8 <= m; j += 8){
        int i0 = __shfl(myidx, j),   i1 = __shfl(myidx, j+1);
        int i2 = __shfl(myidx, j+2), i3 = __shfl(myidx, j+3);
        int i4 = __shfl(myidx, j+4), i5 = __shfl(myidx, j+5);
        int i6 = __shfl(myidx, j+6), i7 = __shfl(myidx, j+7);
        float2 v0 = *(const float2*)&h2[(size_t)i0*DD + c];
        float2 v1 = *(const float2*)&h2[(size_t)i1*DD + c];
        float2 v2 = *(const float2*)&h2[(size_t)i2*DD + c];
        float2 v3 = *(const float2*)&h2[(size_t)i3*DD + c];
        float2 v4 = *(const float2*)&h2[(size_t)i4*DD + c];
        float2 v5 = *(const float2*)&h2[(size_t)i5*DD + c];
        float2 v6 = *(const float2*)&h2[(size_t)i6*DD + c];
        float2 v7 = *(const float2*)&h2[(size_t)i7*DD + c];
        a0 += ((v0.x + v1.x) + (v2.x + v3.x)) + ((v4.x + v5.x) + (v6.x + v7.x));
        a1 += ((v0.y + v1.y) + (v2.y + v3.y)) + ((v4.y + v5.y) + (v6.y + v7.y));
      }
      for (; j + 4 <= m; j += 4){
        int i0 = __shfl(myidx, j),   i1 = __shfl(myidx, j+1);
        int i2 = __shfl(myidx, j+2), i3 = __shfl(myidx, j+3);
        float2 v0 = *(const float2*)&h2[(size_t)i0*DD + c];
        float2 v1 = *(const float2*)&h2[(size_t)i1*DD + c];
        float2 v2 = *(const float2*)&h2[(size_t)i2*DD + c];
        float2 v3 = *(const float2*)&h2[(size_t)i3*DD + c];
        a0 += (v0.x + v1.x) + (v2.x + v3.x);
        a1 += (v0.y + v1.y) + (v2.y + v3.y);
      }
      for (; j < m; j++){
        int i0 = __shfl(myidx, j);
        float2 v0 = *(const float2*)&h2[(size_t)i0*DD + c];
        a0 += v0.x; a1 += v0.y;
      }
    }
    float ndv = ndst[node];
    float v0 = fmaf(a0, ndv, b0), v1 = fmaf(a1, ndv, b1);
    float2 vv; vv.x = v0; vv.y = v1;
    *(float2*)&hout[(size_t)node*DD + c] = vv;
    s0 += v0; s1 += v1; q0 += v0*v0; q1 += v1*v1;
  }
  if (do_stats){
    red[t] = s0; __syncthreads();
    if (t < 64) atomicAdd(&colsum[t*2],   red[t] + red[t+64] + red[t+128] + red[t+192]);
    __syncthreads();
    red[t] = s1; __syncthreads();
    if (t < 64) atomicAdd(&colsum[t*2+1], red[t] + red[t+64] + red[t+128] + red[t+192]);
    __syncthreads();
    red[t] = q0; __syncthreads();
    if (t < 64) atomicAdd(&colsq[t*2],    red[t] + red[t+64] + red[t+128] + red[t+192]);
    __syncthreads();
    red[t] = q1; __syncthreads();
    if (t < 64) atomicAdd(&colsq[t*2+1],  red[t] + red[t+64] + red[t+128] + red[t+192]);
  }
}

// ---------------- BN finalize: per-col scale/shift ----------------
__global__ __launch_bounds__(DD) void bnfin_kernel(const float* __restrict__ colsum, const float* __restrict__ colsq,
                                                   const float* __restrict__ gamma, const float* __restrict__ beta,
                                                   float* __restrict__ ss, int n){
  int c = threadIdx.x;
  float invn = 1.0f / (float)n;
  float mean = colsum[c] * invn;
  float var  = colsq[c] * invn - mean*mean;
  var = fmaxf(var, 0.f);
  float sc = gamma[c] * rsqrtf(var + EPS);
  ss[c] = sc;
  ss[DD + c] = beta[c] - mean*sc;
}

extern "C" void kernel_launch(void* const* d_in, const int* in_sizes, int n_in,
                              void* d_out, int out_size, void* d_ws, size_t ws_size,
                              hipStream_t stream) {
  const float* feat   = (const float*)d_in[0];
  const int*   src    = (const int*)d_in[1];
  const int*   dst    = (const int*)d_in[2];
  const float* Ws     = (const float*)d_in[3];
  const float* bs     = (const float*)d_in[4];
  const float* gammas = (const float*)d_in[5];
  const float* betas  = (const float*)d_in[6];
  float* out = (float*)d_out;

  int n  = in_sizes[0] / DD;   // 50000
  int ne = in_sizes[1];        // 800000

  char* p = (char*)d_ws;
  int* deg_out = (int*)p; p += (size_t)n*sizeof(int);
  int* deg_in  = (int*)p; p += (size_t)n*sizeof(int);
  int* rowptr  = (int*)p; p += (size_t)(n+1)*sizeof(int);
  int* cursor  = (int*)p; p += (size_t)n*sizeof(int);
  int* csr_src = (int*)p; p += (size_t)ne*sizeof(int);
  float* ns      = (float*)p; p += (size_t)n*sizeof(float);
  float* nd      = (float*)p; p += (size_t)n*sizeof(float);
  float* colsum  = (float*)p; p += DD*sizeof(float);
  float* colsq   = (float*)p; p += DD*sizeof(float);
  float* scsh    = (float*)p; p += 2*DD*sizeof(float);
  p = (char*)(((uintptr_t)p + 255) & ~(uintptr_t)255);
  float* B0 = (float*)p; p += (size_t)n*DD*sizeof(float);

  // degrees + norms + CSR build (recomputed every call; ws is poisoned)
  hipMemsetAsync(deg_out, 0, 2*(size_t)n*sizeof(int), stream);   // deg_out,deg_in contiguous
  degree_kernel<<<(ne+255)/256, 256, 0, stream>>>(src, dst, deg_out, deg_in, ne);
  norm_kernel<<<(n+255)/256, 256, 0, stream>>>(deg_out, deg_in, ns, nd, n);
  scan_kernel<<<1, 1024, 0, stream>>>(deg_in, rowptr, n);
  hipMemsetAsync(cursor, 0, (size_t)n*sizeof(int), stream);
  fill_kernel<<<(ne+255)/256, 256, 0, stream>>>(src, dst, rowptr, cursor, csr_src, ne);

  for (int L = 0; L < 3; L++){
    const float* hin = (L == 0) ? feat : out;
    gemm_kernel<<<(n+31)/32, 256, 0, stream>>>(hin, Ws + (size_t)L*DD*DD, ns, scsh, (L > 0) ? 1 : 0, B0, n);
    int do_stats = (L < 2) ? 1 : 0;
    if (do_stats) hipMemsetAsync(colsum, 0, 2*DD*sizeof(float), stream);  // colsum,colsq contiguous
    agg_kernel<<<2048, 256, 0, stream>>>(B0, rowptr, csr_src, nd, bs + (size_t)L*DD, out,
                                         colsum, colsq, do_stats, n);
    if (do_stats) bnfin_kernel<<<1, DD, 0, stream>>>(colsum, colsq, gammas + (size_t)L*DD,
                                                     betas + (size_t)L*DD, scsh, n);
  }
}

// Round 10
// 675.874 us; speedup vs baseline: 1.3502x; 1.2308x over previous
//
#include <hip/hip_runtime.h>
#include <stdint.h>

#define DD 128
#define EPS 1e-5f

static __device__ __forceinline__ void fma4(float4& a, float s, const float4& w){
  a.x = fmaf(s, w.x, a.x); a.y = fmaf(s, w.y, a.y);
  a.z = fmaf(s, w.z, a.z); a.w = fmaf(s, w.w, a.w);
}

static __device__ __forceinline__ unsigned short f2bf(float x){   // RNE f32->bf16
  unsigned u = __float_as_uint(x);
  return (unsigned short)((u + 0x7FFFu + ((u >> 16) & 1u)) >> 16);
}
#define BFLO(v) __uint_as_float(((v) & 0xFFFFu) << 16)
#define BFHI(v) __uint_as_float((v) & 0xFFFF0000u)

// ---------------- degree histogram (also CSR counts) ----------------
__global__ __launch_bounds__(256) void degree_kernel(const int* __restrict__ src, const int* __restrict__ dst,
                                                     int* __restrict__ deg_out, int* __restrict__ deg_in, int ne){
  int e = blockIdx.x*256 + threadIdx.x;
  if (e < ne){
    atomicAdd(&deg_out[src[e]], 1);
    atomicAdd(&deg_in[dst[e]], 1);
  }
}

__global__ __launch_bounds__(256) void norm_kernel(const int* __restrict__ deg_out, const int* __restrict__ deg_in,
                                                   float* __restrict__ ns, float* __restrict__ nd, int n){
  int i = blockIdx.x*256 + threadIdx.x;
  if (i < n){
    int dout = deg_out[i] > 1 ? deg_out[i] : 1;
    int din  = deg_in[i]  > 1 ? deg_in[i]  : 1;
    ns[i] = rsqrtf((float)dout);
    nd[i] = rsqrtf((float)din);
  }
}

// ---------------- single-block prefix sum over deg_in -> rowptr ----------------
__global__ __launch_bounds__(1024) void scan_kernel(const int* __restrict__ counts, int* __restrict__ rowptr, int n){
  __shared__ int wsum[16];
  __shared__ int sbase, snext;
  int t = threadIdx.x, lane = t & 63, w = t >> 6;
  if (t == 0) sbase = 0;
  __syncthreads();
  int ntiles = (n + 1023) >> 10;
  for (int tile = 0; tile < ntiles; tile++){
    int i = (tile << 10) + t;
    int v = (i < n) ? counts[i] : 0;
    int x = v;
    #pragma unroll
    for (int off = 1; off < 64; off <<= 1){
      int u = __shfl_up(x, off);
      if (lane >= off) x += u;
    }
    if (lane == 63) wsum[w] = x;
    __syncthreads();
    if (t == 0){
      int acc = 0;
      #pragma unroll
      for (int k2 = 0; k2 < 16; k2++){ int s = wsum[k2]; wsum[k2] = acc; acc += s; }
      snext = sbase + acc;
    }
    __syncthreads();
    int excl = sbase + wsum[w] + x - v;
    if (i < n) rowptr[i] = excl;
    if (i == n - 1) rowptr[n] = excl + v;
    __syncthreads();
    if (t == 0) sbase = snext;
    __syncthreads();
  }
}

// ---------------- CSR fill (edge id -> slot under its dst) ----------------
__global__ __launch_bounds__(256) void fill_kernel(const int* __restrict__ src, const int* __restrict__ dst,
                                                   const int* __restrict__ rowptr, int* __restrict__ cursor,
                                                   int* __restrict__ csr_src, int ne){
  int e = blockIdx.x*256 + threadIdx.x;
  if (e < ne){
    int d = dst[e];
    int pos = rowptr[d] + atomicAdd(&cursor[d], 1);
    csr_src[pos] = src[e];
  }
}

// ---------------- GEMM: B0(bf16) = f(hin) * nsrc @ W ----------------
// W staged in two 32KB K-halves -> 51KB LDS -> 3 blocks/CU.
// epilogue converts f32 acc -> bf16 rows (halves agg gather bytes).
__global__ __launch_bounds__(256) void gemm_kernel(
    const float* __restrict__ hin, const float* __restrict__ W,
    const float* __restrict__ nsrc, const float* __restrict__ ss, int has_ss,
    unsigned short* __restrict__ hout, int nrows)
{
  __shared__ __align__(16) float lw[64*DD];    // 32 KB (one K-half of W)
  __shared__ __align__(16) float ht[DD*36];    // 18 KB  [k][row] transposed tile
  __shared__ float lsc[DD], lsh[DD];
  int t = threadIdx.x;
  if (t < DD){
    lsc[t] = has_ss ? ss[t]      : 1.0f;
    lsh[t] = has_ss ? ss[DD + t] : 0.0f;
  }
  {
    const float4* W4 = (const float4*)W;
    float4* lw4 = (float4*)lw;
    #pragma unroll
    for (int i = 0; i < 8; i++) lw4[i*256 + t] = W4[i*256 + t];
  }
  __syncthreads();   // lsc/lsh + W half0 visible

  int base = blockIdx.x * 32;
  #pragma unroll
  for (int i = 0; i < 16; i++){
    int idx = i*256 + t;          // 0..4095
    int r = idx >> 7, cc = idx & 127;
    int row = base + r;
    float v = 0.f;
    if (row < nrows){
      v = hin[(size_t)row*DD + cc];
      v = fmaf(v, lsc[cc], lsh[cc]);
      if (has_ss) v = fmaxf(v, 0.f);
      v *= nsrc[row];
    }
    ht[cc*36 + r] = v;
  }
  __syncthreads();

  int j = t & 31, g = t >> 5;
  float4 a0 = {0,0,0,0}, a1 = {0,0,0,0}, a2 = {0,0,0,0}, a3 = {0,0,0,0};
  #pragma unroll 8
  for (int k = 0; k < 64; k++){
    float4 hv = *(const float4*)&ht[k*36 + g*4];
    float4 wv = *(const float4*)&lw[k*DD + j*4];
    fma4(a0, hv.x, wv); fma4(a1, hv.y, wv); fma4(a2, hv.z, wv); fma4(a3, hv.w, wv);
  }
  __syncthreads();
  {
    const float4* W4 = (const float4*)W + 2048;   // K rows 64..127
    float4* lw4 = (float4*)lw;
    #pragma unroll
    for (int i = 0; i < 8; i++) lw4[i*256 + t] = W4[i*256 + t];
  }
  __syncthreads();
  #pragma unroll 8
  for (int k = 64; k < 128; k++){
    float4 hv = *(const float4*)&ht[k*36 + g*4];
    float4 wv = *(const float4*)&lw[(k-64)*DD + j*4];
    fma4(a0, hv.x, wv); fma4(a1, hv.y, wv); fma4(a2, hv.z, wv); fma4(a3, hv.w, wv);
  }
  int r0 = base + g*4;
  ushort4 o;
  if (r0 + 0 < nrows){ o.x=f2bf(a0.x); o.y=f2bf(a0.y); o.z=f2bf(a0.z); o.w=f2bf(a0.w);
    ((ushort4*)hout)[(size_t)(r0+0)*32 + j] = o; }
  if (r0 + 1 < nrows){ o.x=f2bf(a1.x); o.y=f2bf(a1.y); o.z=f2bf(a1.z); o.w=f2bf(a1.w);
    ((ushort4*)hout)[(size_t)(r0+1)*32 + j] = o; }
  if (r0 + 2 < nrows){ o.x=f2bf(a2.x); o.y=f2bf(a2.y); o.z=f2bf(a2.z); o.w=f2bf(a2.w);
    ((ushort4*)hout)[(size_t)(r0+2)*32 + j] = o; }
  if (r0 + 3 < nrows){ o.x=f2bf(a3.x); o.y=f2bf(a3.y); o.z=f2bf(a3.z); o.w=f2bf(a3.w);
    ((ushort4*)hout)[(size_t)(r0+3)*32 + j] = o; }
}

// ---------------- CSR aggregate + epilogue (+ optional BN stats) ----------------
// one wave per node: 64 lanes x 2 bf16 cols (uint load) = 128 cols, 256B/row.
// indices bulk-loaded coalesced + shfl-broadcast, 8-deep unrolled gathers.
__global__ __launch_bounds__(256) void agg_kernel(
    const unsigned short* __restrict__ h2, const int* __restrict__ rowptr,
    const int* __restrict__ csr_src, const float* __restrict__ ndst,
    const float* __restrict__ bias, float* __restrict__ hout,
    float* __restrict__ colsum, float* __restrict__ colsq,
    int do_stats, int nnodes)
{
  __shared__ float red[256];
  int t = threadIdx.x;
  int lane = t & 63, w = t >> 6;
  int slot = blockIdx.x*4 + w, nslots = gridDim.x*4;
  int c = lane*2;
  float b0 = bias[c], b1 = bias[c+1];
  float s0 = 0, s1 = 0, q0 = 0, q1 = 0;
  for (int node = slot; node < nnodes; node += nslots){
    int beg = rowptr[node], end = rowptr[node+1];
    int cnt = end - beg;
    float a0 = 0.f, a1 = 0.f;
    for (int bse = 0; bse < cnt; bse += 64){
      int m = cnt - bse; if (m > 64) m = 64;
      int myidx = (bse + lane < cnt) ? csr_src[beg + bse + lane] : 0;
      int j = 0;
      for (; j + 8 <= m; j += 8){
        int i0 = __shfl(myidx, j),   i1 = __shfl(myidx, j+1);
        int i2 = __shfl(myidx, j+2), i3 = __shfl(myidx, j+3);
        int i4 = __shfl(myidx, j+4), i5 = __shfl(myidx, j+5);
        int i6 = __shfl(myidx, j+6), i7 = __shfl(myidx, j+7);
        unsigned v0 = *(const unsigned*)&h2[(size_t)i0*DD + c];
        unsigned v1 = *(const unsigned*)&h2[(size_t)i1*DD + c];
        unsigned v2 = *(const unsigned*)&h2[(size_t)i2*DD + c];
        unsigned v3 = *(const unsigned*)&h2[(size_t)i3*DD + c];
        unsigned v4 = *(const unsigned*)&h2[(size_t)i4*DD + c];
        unsigned v5 = *(const unsigned*)&h2[(size_t)i5*DD + c];
        unsigned v6 = *(const unsigned*)&h2[(size_t)i6*DD + c];
        unsigned v7 = *(const unsigned*)&h2[(size_t)i7*DD + c];
        a0 += ((BFLO(v0) + BFLO(v1)) + (BFLO(v2) + BFLO(v3))) + ((BFLO(v4) + BFLO(v5)) + (BFLO(v6) + BFLO(v7)));
        a1 += ((BFHI(v0) + BFHI(v1)) + (BFHI(v2) + BFHI(v3))) + ((BFHI(v4) + BFHI(v5)) + (BFHI(v6) + BFHI(v7)));
      }
      for (; j + 4 <= m; j += 4){
        int i0 = __shfl(myidx, j),   i1 = __shfl(myidx, j+1);
        int i2 = __shfl(myidx, j+2), i3 = __shfl(myidx, j+3);
        unsigned v0 = *(const unsigned*)&h2[(size_t)i0*DD + c];
        unsigned v1 = *(const unsigned*)&h2[(size_t)i1*DD + c];
        unsigned v2 = *(const unsigned*)&h2[(size_t)i2*DD + c];
        unsigned v3 = *(const unsigned*)&h2[(size_t)i3*DD + c];
        a0 += (BFLO(v0) + BFLO(v1)) + (BFLO(v2) + BFLO(v3));
        a1 += (BFHI(v0) + BFHI(v1)) + (BFHI(v2) + BFHI(v3));
      }
      for (; j < m; j++){
        int i0 = __shfl(myidx, j);
        unsigned v0 = *(const unsigned*)&h2[(size_t)i0*DD + c];
        a0 += BFLO(v0); a1 += BFHI(v0);
      }
    }
    float ndv = ndst[node];
    float v0 = fmaf(a0, ndv, b0), v1 = fmaf(a1, ndv, b1);
    float2 vv; vv.x = v0; vv.y = v1;
    *(float2*)&hout[(size_t)node*DD + c] = vv;
    s0 += v0; s1 += v1; q0 += v0*v0; q1 += v1*v1;
  }
  if (do_stats){
    red[t] = s0; __syncthreads();
    if (t < 64) atomicAdd(&colsum[t*2],   red[t] + red[t+64] + red[t+128] + red[t+192]);
    __syncthreads();
    red[t] = s1; __syncthreads();
    if (t < 64) atomicAdd(&colsum[t*2+1], red[t] + red[t+64] + red[t+128] + red[t+192]);
    __syncthreads();
    red[t] = q0; __syncthreads();
    if (t < 64) atomicAdd(&colsq[t*2],    red[t] + red[t+64] + red[t+128] + red[t+192]);
    __syncthreads();
    red[t] = q1; __syncthreads();
    if (t < 64) atomicAdd(&colsq[t*2+1],  red[t] + red[t+64] + red[t+128] + red[t+192]);
  }
}

// ---------------- BN finalize: per-col scale/shift ----------------
__global__ __launch_bounds__(DD) void bnfin_kernel(const float* __restrict__ colsum, const float* __restrict__ colsq,
                                                   const float* __restrict__ gamma, const float* __restrict__ beta,
                                                   float* __restrict__ ss, int n){
  int c = threadIdx.x;
  float invn = 1.0f / (float)n;
  float mean = colsum[c] * invn;
  float var  = colsq[c] * invn - mean*mean;
  var = fmaxf(var, 0.f);
  float sc = gamma[c] * rsqrtf(var + EPS);
  ss[c] = sc;
  ss[DD + c] = beta[c] - mean*sc;
}

extern "C" void kernel_launch(void* const* d_in, const int* in_sizes, int n_in,
                              void* d_out, int out_size, void* d_ws, size_t ws_size,
                              hipStream_t stream) {
  const float* feat   = (const float*)d_in[0];
  const int*   src    = (const int*)d_in[1];
  const int*   dst    = (const int*)d_in[2];
  const float* Ws     = (const float*)d_in[3];
  const float* bs     = (const float*)d_in[4];
  const float* gammas = (const float*)d_in[5];
  const float* betas  = (const float*)d_in[6];
  float* out = (float*)d_out;

  int n  = in_sizes[0] / DD;   // 50000
  int ne = in_sizes[1];        // 800000

  char* p = (char*)d_ws;
  int* deg_out = (int*)p; p += (size_t)n*sizeof(int);
  int* deg_in  = (int*)p; p += (size_t)n*sizeof(int);
  int* rowptr  = (int*)p; p += (size_t)(n+1)*sizeof(int);
  int* cursor  = (int*)p; p += (size_t)n*sizeof(int);
  int* csr_src = (int*)p; p += (size_t)ne*sizeof(int);
  float* ns      = (float*)p; p += (size_t)n*sizeof(float);
  float* nd      = (float*)p; p += (size_t)n*sizeof(float);
  float* colsum  = (float*)p; p += DD*sizeof(float);
  float* colsq   = (float*)p; p += DD*sizeof(float);
  float* scsh    = (float*)p; p += 2*DD*sizeof(float);
  p = (char*)(((uintptr_t)p + 255) & ~(uintptr_t)255);
  unsigned short* B0 = (unsigned short*)p; p += (size_t)n*DD*sizeof(unsigned short);

  // degrees + norms + CSR build (recomputed every call; ws is poisoned)
  hipMemsetAsync(deg_out, 0, 2*(size_t)n*sizeof(int), stream);   // deg_out,deg_in contiguous
  degree_kernel<<<(ne+255)/256, 256, 0, stream>>>(src, dst, deg_out, deg_in, ne);
  norm_kernel<<<(n+255)/256, 256, 0, stream>>>(deg_out, deg_in, ns, nd, n);
  scan_kernel<<<1, 1024, 0, stream>>>(deg_in, rowptr, n);
  hipMemsetAsync(cursor, 0, (size_t)n*sizeof(int), stream);
  fill_kernel<<<(ne+255)/256, 256, 0, stream>>>(src, dst, rowptr, cursor, csr_src, ne);

  for (int L = 0; L < 3; L++){
    const float* hin = (L == 0) ? feat : out;
    gemm_kernel<<<(n+31)/32, 256, 0, stream>>>(hin, Ws + (size_t)L*DD*DD, ns, scsh, (L > 0) ? 1 : 0, B0, n);
    int do_stats = (L < 2) ? 1 : 0;
    if (do_stats) hipMemsetAsync(colsum, 0, 2*DD*sizeof(float), stream);  // colsum,colsq contiguous
    agg_kernel<<<2048, 256, 0, stream>>>(B0, rowptr, csr_src, nd, bs + (size_t)L*DD, out,
                                         colsum, colsq, do_stats, n);
    if (do_stats) bnfin_kernel<<<1, DD, 0, stream>>>(colsum, colsq, gammas + (size_t)L*DD,
                                                     betas + (size_t)L*DD, scsh, n);
  }
}

// Round 13
// 580.192 us; speedup vs baseline: 1.5728x; 1.1649x over previous
//
#include <hip/hip_runtime.h>
#include <stdint.h>

#define DD 128
#define EPS 1e-5f

static __device__ __forceinline__ void fma4(float4& a, float s, const float4& w){
  a.x = fmaf(s, w.x, a.x); a.y = fmaf(s, w.y, a.y);
  a.z = fmaf(s, w.z, a.z); a.w = fmaf(s, w.w, a.w);
}

static __device__ __forceinline__ unsigned short f2bf(float x){   // RNE f32->bf16
  unsigned u = __float_as_uint(x);
  return (unsigned short)((u + 0x7FFFu + ((u >> 16) & 1u)) >> 16);
}
#define BFLO(v) __uint_as_float(((v) & 0xFFFFu) << 16)
#define BFHI(v) __uint_as_float((v) & 0xFFFF0000u)

// ---------------- degree histogram (also CSR counts) ----------------
__global__ __launch_bounds__(256) void degree_kernel(const int* __restrict__ src, const int* __restrict__ dst,
                                                     int* __restrict__ deg_out, int* __restrict__ deg_in, int ne){
  int e = blockIdx.x*256 + threadIdx.x;
  if (e < ne){
    atomicAdd(&deg_out[src[e]], 1);
    atomicAdd(&deg_in[dst[e]], 1);
  }
}

__global__ __launch_bounds__(256) void norm_kernel(const int* __restrict__ deg_out, const int* __restrict__ deg_in,
                                                   float* __restrict__ ns, float* __restrict__ nd, int n){
  int i = blockIdx.x*256 + threadIdx.x;
  if (i < n){
    int dout = deg_out[i] > 1 ? deg_out[i] : 1;
    int din  = deg_in[i]  > 1 ? deg_in[i]  : 1;
    ns[i] = rsqrtf((float)dout);
    nd[i] = rsqrtf((float)din);
  }
}

// ---------------- single-block prefix sum over deg_in -> rowptr ----------------
__global__ __launch_bounds__(1024) void scan_kernel(const int* __restrict__ counts, int* __restrict__ rowptr, int n){
  __shared__ int wsum[16];
  __shared__ int sbase, snext;
  int t = threadIdx.x, lane = t & 63, w = t >> 6;
  if (t == 0) sbase = 0;
  __syncthreads();
  int ntiles = (n + 1023) >> 10;
  for (int tile = 0; tile < ntiles; tile++){
    int i = (tile << 10) + t;
    int v = (i < n) ? counts[i] : 0;
    int x = v;
    #pragma unroll
    for (int off = 1; off < 64; off <<= 1){
      int u = __shfl_up(x, off);
      if (lane >= off) x += u;
    }
    if (lane == 63) wsum[w] = x;
    __syncthreads();
    if (t == 0){
      int acc = 0;
      #pragma unroll
      for (int k2 = 0; k2 < 16; k2++){ int s = wsum[k2]; wsum[k2] = acc; acc += s; }
      snext = sbase + acc;
    }
    __syncthreads();
    int excl = sbase + wsum[w] + x - v;
    if (i < n) rowptr[i] = excl;
    if (i == n - 1) rowptr[n] = excl + v;
    __syncthreads();
    if (t == 0) sbase = snext;
    __syncthreads();
  }
}

// ---------------- CSR fill (edge id -> slot under its dst) ----------------
__global__ __launch_bounds__(256) void fill_kernel(const int* __restrict__ src, const int* __restrict__ dst,
                                                   const int* __restrict__ rowptr, int* __restrict__ cursor,
                                                   int* __restrict__ csr_src, int ne){
  int e = blockIdx.x*256 + threadIdx.x;
  if (e < ne){
    int d = dst[e];
    int pos = rowptr[d] + atomicAdd(&cursor[d], 1);
    csr_src[pos] = src[e];
  }
}

// ---------------- GEMM: B0(bf16) = f(hin) * nsrc @ W ----------------
// W staged in two 32KB K-halves -> 51KB LDS -> 3 blocks/CU.
__global__ __launch_bounds__(256) void gemm_kernel(
    const float* __restrict__ hin, const float* __restrict__ W,
    const float* __restrict__ nsrc, const float* __restrict__ ss, int has_ss,
    unsigned short* __restrict__ hout, int nrows)
{
  __shared__ __align__(16) float lw[64*DD];    // 32 KB (one K-half of W)
  __shared__ __align__(16) float ht[DD*36];    // 18 KB  [k][row] transposed tile
  __shared__ float lsc[DD], lsh[DD];
  int t = threadIdx.x;
  if (t < DD){
    lsc[t] = has_ss ? ss[t]      : 1.0f;
    lsh[t] = has_ss ? ss[DD + t] : 0.0f;
  }
  {
    const float4* W4 = (const float4*)W;
    float4* lw4 = (float4*)lw;
    #pragma unroll
    for (int i = 0; i < 8; i++) lw4[i*256 + t] = W4[i*256 + t];
  }
  __syncthreads();   // lsc/lsh + W half0 visible

  int base = blockIdx.x * 32;
  #pragma unroll
  for (int i = 0; i < 16; i++){
    int idx = i*256 + t;          // 0..4095
    int r = idx >> 7, cc = idx & 127;
    int row = base + r;
    float v = 0.f;
    if (row < nrows){
      v = hin[(size_t)row*DD + cc];
      v = fmaf(v, lsc[cc], lsh[cc]);
      if (has_ss) v = fmaxf(v, 0.f);
      v *= nsrc[row];
    }
    ht[cc*36 + r] = v;
  }
  __syncthreads();

  int j = t & 31, g = t >> 5;
  float4 a0 = {0,0,0,0}, a1 = {0,0,0,0}, a2 = {0,0,0,0}, a3 = {0,0,0,0};
  #pragma unroll 8
  for (int k = 0; k < 64; k++){
    float4 hv = *(const float4*)&ht[k*36 + g*4];
    float4 wv = *(const float4*)&lw[k*DD + j*4];
    fma4(a0, hv.x, wv); fma4(a1, hv.y, wv); fma4(a2, hv.z, wv); fma4(a3, hv.w, wv);
  }
  __syncthreads();
  {
    const float4* W4 = (const float4*)W + 2048;   // K rows 64..127
    float4* lw4 = (float4*)lw;
    #pragma unroll
    for (int i = 0; i < 8; i++) lw4[i*256 + t] = W4[i*256 + t];
  }
  __syncthreads();
  #pragma unroll 8
  for (int k = 64; k < 128; k++){
    float4 hv = *(const float4*)&ht[k*36 + g*4];
    float4 wv = *(const float4*)&lw[(k-64)*DD + j*4];
    fma4(a0, hv.x, wv); fma4(a1, hv.y, wv); fma4(a2, hv.z, wv); fma4(a3, hv.w, wv);
  }
  int r0 = base + g*4;
  ushort4 o;
  if (r0 + 0 < nrows){ o.x=f2bf(a0.x); o.y=f2bf(a0.y); o.z=f2bf(a0.z); o.w=f2bf(a0.w);
    ((ushort4*)hout)[(size_t)(r0+0)*32 + j] = o; }
  if (r0 + 1 < nrows){ o.x=f2bf(a1.x); o.y=f2bf(a1.y); o.z=f2bf(a1.z); o.w=f2bf(a1.w);
    ((ushort4*)hout)[(size_t)(r0+1)*32 + j] = o; }
  if (r0 + 2 < nrows){ o.x=f2bf(a2.x); o.y=f2bf(a2.y); o.z=f2bf(a2.z); o.w=f2bf(a2.w);
    ((ushort4*)hout)[(size_t)(r0+2)*32 + j] = o; }
  if (r0 + 3 < nrows){ o.x=f2bf(a3.x); o.y=f2bf(a3.y); o.z=f2bf(a3.z); o.w=f2bf(a3.w);
    ((ushort4*)hout)[(size_t)(r0+3)*32 + j] = o; }
}

// ---------------- CSR aggregate + epilogue (+ optional BN stats) ----------------
// one wave per node; FOUR 16-lane quarters each gather a full 256B bf16 row as
// uint4 (16B/lane) -> 4 edges per gather instruction. Quarter combine via
// shfl_xor(16,32) once per node; quarter 0 writes row + stats.
__global__ __launch_bounds__(256) void agg_kernel(
    const unsigned short* __restrict__ h2, const int* __restrict__ rowptr,
    const int* __restrict__ csr_src, const float* __restrict__ ndst,
    const float* __restrict__ bias, float* __restrict__ hout,
    float* __restrict__ colsum, float* __restrict__ colsq,
    int do_stats, int nnodes)
{
  __shared__ float red[4][DD];
  int t = threadIdx.x;
  int lane = t & 63, w = t >> 6;
  int qid = lane >> 4, sub = lane & 15;
  int slot = blockIdx.x*4 + w, nslots = gridDim.x*4;
  const uint4* h4 = (const uint4*)h2;     // one bf16 row = 16 uint4
  float bcol[8];
  #pragma unroll
  for (int k = 0; k < 8; k++) bcol[k] = bias[sub*8 + k];
  float s[8], q[8];
  #pragma unroll
  for (int k = 0; k < 8; k++){ s[k] = 0.f; q[k] = 0.f; }

  for (int node = slot; node < nnodes; node += nslots){
    int beg = rowptr[node], end = rowptr[node+1];
    int cnt = end - beg;
    float a[8];
    #pragma unroll
    for (int k = 0; k < 8; k++) a[k] = 0.f;
    for (int bse = 0; bse < cnt; bse += 64){
      int m = cnt - bse; if (m > 64) m = 64;
      int myidx = (bse + lane < cnt) ? csr_src[beg + bse + lane] : 0;
      #pragma unroll 4
      for (int jj = 0; jj < m; jj += 4){
        int e = jj + qid;
        int idx = __shfl(myidx, e);        // source lane e <= 63 always
        if (e < m){                        // quarter-uniform predicate
          uint4 v = h4[(size_t)idx*16 + sub];
          a[0] += BFLO(v.x); a[1] += BFHI(v.x);
          a[2] += BFLO(v.y); a[3] += BFHI(v.y);
          a[4] += BFLO(v.z); a[5] += BFHI(v.z);
          a[6] += BFLO(v.w); a[7] += BFHI(v.w);
        }
      }
    }
    // combine the 4 quarters (lane = qid*16 + sub; xor 16/32 toggles qid bits)
    #pragma unroll
    for (int k = 0; k < 8; k++){
      a[k] += __shfl_xor(a[k], 16);
      a[k] += __shfl_xor(a[k], 32);
    }
    float ndv = ndst[node];
    float v[8];
    #pragma unroll
    for (int k = 0; k < 8; k++) v[k] = fmaf(a[k], ndv, bcol[k]);
    if (qid == 0){
      float4 o0, o1;
      o0.x = v[0]; o0.y = v[1]; o0.z = v[2]; o0.w = v[3];
      o1.x = v[4]; o1.y = v[5]; o1.z = v[6]; o1.w = v[7];
      *(float4*)&hout[(size_t)node*DD + sub*8]     = o0;
      *(float4*)&hout[(size_t)node*DD + sub*8 + 4] = o1;
      #pragma unroll
      for (int k = 0; k < 8; k++){ s[k] += v[k]; q[k] += v[k]*v[k]; }
    }
  }
  if (do_stats){
    if (qid == 0){
      #pragma unroll
      for (int k = 0; k < 8; k++) red[w][sub*8 + k] = s[k];
    }
    __syncthreads();
    if (t < DD) atomicAdd(&colsum[t], red[0][t] + red[1][t] + red[2][t] + red[3][t]);
    __syncthreads();
    if (qid == 0){
      #pragma unroll
      for (int k = 0; k < 8; k++) red[w][sub*8 + k] = q[k];
    }
    __syncthreads();
    if (t < DD) atomicAdd(&colsq[t], red[0][t] + red[1][t] + red[2][t] + red[3][t]);
  }
}

// ---------------- BN finalize: per-col scale/shift ----------------
__global__ __launch_bounds__(DD) void bnfin_kernel(const float* __restrict__ colsum, const float* __restrict__ colsq,
                                                   const float* __restrict__ gamma, const float* __restrict__ beta,
                                                   float* __restrict__ ss, int n){
  int c = threadIdx.x;
  float invn = 1.0f / (float)n;
  float mean = colsum[c] * invn;
  float var  = colsq[c] * invn - mean*mean;
  var = fmaxf(var, 0.f);
  float sc = gamma[c] * rsqrtf(var + EPS);
  ss[c] = sc;
  ss[DD + c] = beta[c] - mean*sc;
}

extern "C" void kernel_launch(void* const* d_in, const int* in_sizes, int n_in,
                              void* d_out, int out_size, void* d_ws, size_t ws_size,
                              hipStream_t stream) {
  const float* feat   = (const float*)d_in[0];
  const int*   src    = (const int*)d_in[1];
  const int*   dst    = (const int*)d_in[2];
  const float* Ws     = (const float*)d_in[3];
  const float* bs     = (const float*)d_in[4];
  const float* gammas = (const float*)d_in[5];
  const float* betas  = (const float*)d_in[6];
  float* out = (float*)d_out;

  int n  = in_sizes[0] / DD;   // 50000
  int ne = in_sizes[1];        // 800000

  char* p = (char*)d_ws;
  int* deg_out = (int*)p; p += (size_t)n*sizeof(int);
  int* deg_in  = (int*)p; p += (size_t)n*sizeof(int);
  int* rowptr  = (int*)p; p += (size_t)(n+1)*sizeof(int);
  int* cursor  = (int*)p; p += (size_t)n*sizeof(int);
  int* csr_src = (int*)p; p += (size_t)ne*sizeof(int);
  float* ns      = (float*)p; p += (size_t)n*sizeof(float);
  float* nd      = (float*)p; p += (size_t)n*sizeof(float);
  float* colsum  = (float*)p; p += DD*sizeof(float);
  float* colsq   = (float*)p; p += DD*sizeof(float);
  float* scsh    = (float*)p; p += 2*DD*sizeof(float);
  p = (char*)(((uintptr_t)p + 255) & ~(uintptr_t)255);
  unsigned short* B0 = (unsigned short*)p; p += (size_t)n*DD*sizeof(unsigned short);

  // degrees + norms + CSR build (recomputed every call; ws is poisoned)
  hipMemsetAsync(deg_out, 0, 2*(size_t)n*sizeof(int), stream);   // deg_out,deg_in contiguous
  degree_kernel<<<(ne+255)/256, 256, 0, stream>>>(src, dst, deg_out, deg_in, ne);
  norm_kernel<<<(n+255)/256, 256, 0, stream>>>(deg_out, deg_in, ns, nd, n);
  scan_kernel<<<1, 1024, 0, stream>>>(deg_in, rowptr, n);
  hipMemsetAsync(cursor, 0, (size_t)n*sizeof(int), stream);
  fill_kernel<<<(ne+255)/256, 256, 0, stream>>>(src, dst, rowptr, cursor, csr_src, ne);

  for (int L = 0; L < 3; L++){
    const float* hin = (L == 0) ? feat : out;
    gemm_kernel<<<(n+31)/32, 256, 0, stream>>>(hin, Ws + (size_t)L*DD*DD, ns, scsh, (L > 0) ? 1 : 0, B0, n);
    int do_stats = (L < 2) ? 1 : 0;
    if (do_stats) hipMemsetAsync(colsum, 0, 2*DD*sizeof(float), stream);  // colsum,colsq contiguous
    agg_kernel<<<2048, 256, 0, stream>>>(B0, rowptr, csr_src, nd, bs + (size_t)L*DD, out,
                                         colsum, colsq, do_stats, n);
    if (do_stats) bnfin_kernel<<<1, DD, 0, stream>>>(colsum, colsq, gammas + (size_t)L*DD,
                                                     betas + (size_t)L*DD, scsh, n);
  }
}

// Round 15
// 523.615 us; speedup vs baseline: 1.7428x; 1.1081x over previous
//
#include <hip/hip_runtime.h>
#include <stdint.h>

#define DD 128
#define EPS 1e-5f

typedef short s8v __attribute__((ext_vector_type(8)));
typedef float f4v __attribute__((ext_vector_type(4)));

static __device__ __forceinline__ unsigned short f2bf(float x){   // RNE f32->bf16
  unsigned u = __float_as_uint(x);
  return (unsigned short)((u + 0x7FFFu + ((u >> 16) & 1u)) >> 16);
}
#define BFLO(v) __uint_as_float(((v) & 0xFFFFu) << 16)
#define BFHI(v) __uint_as_float((v) & 0xFFFF0000u)

// swizzled byte offset into a row-major bf16 array with 256B row stride
static __device__ __forceinline__ int swzoff(int row, int k8){
  return row*256 + ((k8 ^ (row & 7)) << 4);
}

// ---------------- degree histogram (also CSR counts) ----------------
__global__ __launch_bounds__(256) void degree_kernel(const int* __restrict__ src, const int* __restrict__ dst,
                                                     int* __restrict__ deg_out, int* __restrict__ deg_in, int ne){
  int e = blockIdx.x*256 + threadIdx.x;
  if (e < ne){
    atomicAdd(&deg_out[src[e]], 1);
    atomicAdd(&deg_in[dst[e]], 1);
  }
}

__global__ __launch_bounds__(256) void norm_kernel(const int* __restrict__ deg_out, const int* __restrict__ deg_in,
                                                   float* __restrict__ ns, float* __restrict__ nd, int n){
  int i = blockIdx.x*256 + threadIdx.x;
  if (i < n){
    int dout = deg_out[i] > 1 ? deg_out[i] : 1;
    int din  = deg_in[i]  > 1 ? deg_in[i]  : 1;
    ns[i] = rsqrtf((float)dout);
    nd[i] = rsqrtf((float)din);
  }
}

// ---------------- single-block prefix sum over deg_in -> rowptr ----------------
__global__ __launch_bounds__(1024) void scan_kernel(const int* __restrict__ counts, int* __restrict__ rowptr, int n){
  __shared__ int wsum[16];
  __shared__ int sbase, snext;
  int t = threadIdx.x, lane = t & 63, w = t >> 6;
  if (t == 0) sbase = 0;
  __syncthreads();
  int ntiles = (n + 1023) >> 10;
  for (int tile = 0; tile < ntiles; tile++){
    int i = (tile << 10) + t;
    int v = (i < n) ? counts[i] : 0;
    int x = v;
    #pragma unroll
    for (int off = 1; off < 64; off <<= 1){
      int u = __shfl_up(x, off);
      if (lane >= off) x += u;
    }
    if (lane == 63) wsum[w] = x;
    __syncthreads();
    if (t == 0){
      int acc = 0;
      #pragma unroll
      for (int k2 = 0; k2 < 16; k2++){ int s = wsum[k2]; wsum[k2] = acc; acc += s; }
      snext = sbase + acc;
    }
    __syncthreads();
    int excl = sbase + wsum[w] + x - v;
    if (i < n) rowptr[i] = excl;
    if (i == n - 1) rowptr[n] = excl + v;
    __syncthreads();
    if (t == 0) sbase = snext;
    __syncthreads();
  }
}

// ---------------- CSR fill (edge id -> slot under its dst) ----------------
__global__ __launch_bounds__(256) void fill_kernel(const int* __restrict__ src, const int* __restrict__ dst,
                                                   const int* __restrict__ rowptr, int* __restrict__ cursor,
                                                   int* __restrict__ csr_src, int ne){
  int e = blockIdx.x*256 + threadIdx.x;
  if (e < ne){
    int d = dst[e];
    int pos = rowptr[d] + atomicAdd(&cursor[d], 1);
    csr_src[pos] = src[e];
  }
}

// ---------------- GEMM (bf16 MFMA): B0(bf16) = f(hin)*nsrc @ W ----------------
// 64-row tile, 4 waves; h and W^T staged as bf16 in XOR-swizzled LDS;
// each wave: 16 rows x 128 cols = 8 col-tiles x 4 K-steps of mfma_16x16x32_bf16.
__global__ __launch_bounds__(256) void gemm_kernel(
    const float* __restrict__ hin, const float* __restrict__ W,
    const float* __restrict__ nsrc, const float* __restrict__ ss, int has_ss,
    unsigned short* __restrict__ hout, int nrows)
{
  __shared__ __align__(16) unsigned short w_lds[DD*DD];   // 32 KB, [col][k] bf16 swizzled
  __shared__ __align__(16) unsigned short h_lds[64*DD];   // 16 KB, [row][k] bf16 swizzled
  __shared__ float lsc[DD], lsh[DD];
  int t = threadIdx.x;
  if (t < DD){
    lsc[t] = has_ss ? ss[t]      : 1.0f;
    lsh[t] = has_ss ? ss[DD + t] : 0.0f;
  }
  __syncthreads();

  // stage W transposed -> w_lds[col][k] (bf16, swizzled)
  {
    int c = t >> 1, khalf = t & 1;
    char* wb = (char*)w_lds;
    #pragma unroll
    for (int i8 = 0; i8 < 8; i8++){
      int k0 = khalf*64 + i8*8;
      unsigned short o[8];
      #pragma unroll
      for (int j = 0; j < 8; j++) o[j] = f2bf(W[(size_t)(k0+j)*DD + c]);
      uint4 pv;
      pv.x = (unsigned)o[0] | ((unsigned)o[1] << 16);
      pv.y = (unsigned)o[2] | ((unsigned)o[3] << 16);
      pv.z = (unsigned)o[4] | ((unsigned)o[5] << 16);
      pv.w = (unsigned)o[6] | ((unsigned)o[7] << 16);
      *(uint4*)(wb + swzoff(c, khalf*8 + i8)) = pv;
    }
  }
  // stage h rows (f32 math: BN/relu/nsrc, then bf16) -> h_lds (swizzled)
  int mbase = blockIdx.x * 64;
  {
    char* hb = (char*)h_lds;
    #pragma unroll
    for (int i = 0; i < 4; i++){
      int s = i*256 + t;           // 0..1023
      int row = s >> 4, k8 = s & 15;
      int grow = mbase + row;
      uint4 pv = {0,0,0,0};
      if (grow < nrows){
        float4 p0 = *(const float4*)&hin[(size_t)grow*DD + k8*8];
        float4 p1 = *(const float4*)&hin[(size_t)grow*DD + k8*8 + 4];
        float nsv = nsrc[grow];
        float vv[8] = {p0.x,p0.y,p0.z,p0.w,p1.x,p1.y,p1.z,p1.w};
        unsigned short o[8];
        #pragma unroll
        for (int j = 0; j < 8; j++){
          int col = k8*8 + j;
          float v = fmaf(vv[j], lsc[col], lsh[col]);
          if (has_ss) v = fmaxf(v, 0.f);
          o[j] = f2bf(v * nsv);
        }
        pv.x = (unsigned)o[0] | ((unsigned)o[1] << 16);
        pv.y = (unsigned)o[2] | ((unsigned)o[3] << 16);
        pv.z = (unsigned)o[4] | ((unsigned)o[5] << 16);
        pv.w = (unsigned)o[6] | ((unsigned)o[7] << 16);
      }
      *(uint4*)(hb + swzoff(row, k8)) = pv;
    }
  }
  __syncthreads();

  int lane = t & 63, w = t >> 6;
  int lrow = lane & 15, lgrp = lane >> 4;       // A row / B col within 16; k-group
  f4v acc[8];
  #pragma unroll
  for (int ct = 0; ct < 8; ct++) acc[ct] = (f4v){0.f,0.f,0.f,0.f};
  const char* hb = (const char*)h_lds;
  const char* wb = (const char*)w_lds;
  #pragma unroll
  for (int ks = 0; ks < 4; ks++){
    int k8 = ks*4 + lgrp;
    int arow = w*16 + lrow;
    s8v a = *(const s8v*)(hb + swzoff(arow, k8));
    #pragma unroll
    for (int ct = 0; ct < 8; ct++){
      int bcol = ct*16 + lrow;
      s8v b = *(const s8v*)(wb + swzoff(bcol, k8));
      acc[ct] = __builtin_amdgcn_mfma_f32_16x16x32_bf16(a, b, acc[ct], 0, 0, 0);
    }
  }
  // epilogue: D[row=(lane>>4)*4+r][col=ct*16+(lane&15)] -> bf16 store
  #pragma unroll
  for (int ct = 0; ct < 8; ct++){
    #pragma unroll
    for (int r = 0; r < 4; r++){
      int grow = mbase + w*16 + lgrp*4 + r;
      if (grow < nrows)
        hout[(size_t)grow*DD + ct*16 + lrow] = f2bf(acc[ct][r]);
    }
  }
}

// ---------------- CSR aggregate + epilogue (+ optional BN stats) ----------------
// one wave per node; FOUR 16-lane quarters each gather a full 256B bf16 row as
// uint4 (16B/lane) -> 4 edges per gather instruction. Quarter combine via
// shfl_xor(16,32) once per node; quarter 0 writes row + stats.
__global__ __launch_bounds__(256) void agg_kernel(
    const unsigned short* __restrict__ h2, const int* __restrict__ rowptr,
    const int* __restrict__ csr_src, const float* __restrict__ ndst,
    const float* __restrict__ bias, float* __restrict__ hout,
    float* __restrict__ colsum, float* __restrict__ colsq,
    int do_stats, int nnodes)
{
  __shared__ float red[4][DD];
  int t = threadIdx.x;
  int lane = t & 63, w = t >> 6;
  int qid = lane >> 4, sub = lane & 15;
  int slot = blockIdx.x*4 + w, nslots = gridDim.x*4;
  const uint4* h4 = (const uint4*)h2;     // one bf16 row = 16 uint4
  float bcol[8];
  #pragma unroll
  for (int k = 0; k < 8; k++) bcol[k] = bias[sub*8 + k];
  float s[8], q[8];
  #pragma unroll
  for (int k = 0; k < 8; k++){ s[k] = 0.f; q[k] = 0.f; }

  for (int node = slot; node < nnodes; node += nslots){
    int beg = rowptr[node], end = rowptr[node+1];
    int cnt = end - beg;
    float a[8];
    #pragma unroll
    for (int k = 0; k < 8; k++) a[k] = 0.f;
    for (int bse = 0; bse < cnt; bse += 64){
      int m = cnt - bse; if (m > 64) m = 64;
      int myidx = (bse + lane < cnt) ? csr_src[beg + bse + lane] : 0;
      #pragma unroll 4
      for (int jj = 0; jj < m; jj += 4){
        int e = jj + qid;
        int idx = __shfl(myidx, e);        // source lane e <= 63 always
        if (e < m){                        // quarter-uniform predicate
          uint4 v = h4[(size_t)idx*16 + sub];
          a[0] += BFLO(v.x); a[1] += BFHI(v.x);
          a[2] += BFLO(v.y); a[3] += BFHI(v.y);
          a[4] += BFLO(v.z); a[5] += BFHI(v.z);
          a[6] += BFLO(v.w); a[7] += BFHI(v.w);
        }
      }
    }
    // combine the 4 quarters (lane = qid*16 + sub; xor 16/32 toggles qid bits)
    #pragma unroll
    for (int k = 0; k < 8; k++){
      a[k] += __shfl_xor(a[k], 16);
      a[k] += __shfl_xor(a[k], 32);
    }
    float ndv = ndst[node];
    float v[8];
    #pragma unroll
    for (int k = 0; k < 8; k++) v[k] = fmaf(a[k], ndv, bcol[k]);
    if (qid == 0){
      float4 o0, o1;
      o0.x = v[0]; o0.y = v[1]; o0.z = v[2]; o0.w = v[3];
      o1.x = v[4]; o1.y = v[5]; o1.z = v[6]; o1.w = v[7];
      *(float4*)&hout[(size_t)node*DD + sub*8]     = o0;
      *(float4*)&hout[(size_t)node*DD + sub*8 + 4] = o1;
      #pragma unroll
      for (int k = 0; k < 8; k++){ s[k] += v[k]; q[k] += v[k]*v[k]; }
    }
  }
  if (do_stats){
    if (qid == 0){
      #pragma unroll
      for (int k = 0; k < 8; k++) red[w][sub*8 + k] = s[k];
    }
    __syncthreads();
    if (t < DD) atomicAdd(&colsum[t], red[0][t] + red[1][t] + red[2][t] + red[3][t]);
    __syncthreads();
    if (qid == 0){
      #pragma unroll
      for (int k = 0; k < 8; k++) red[w][sub*8 + k] = q[k];
    }
    __syncthreads();
    if (t < DD) atomicAdd(&colsq[t], red[0][t] + red[1][t] + red[2][t] + red[3][t]);
  }
}

// ---------------- BN finalize: per-col scale/shift ----------------
__global__ __launch_bounds__(DD) void bnfin_kernel(const float* __restrict__ colsum, const float* __restrict__ colsq,
                                                   const float* __restrict__ gamma, const float* __restrict__ beta,
                                                   float* __restrict__ ss, int n){
  int c = threadIdx.x;
  float invn = 1.0f / (float)n;
  float mean = colsum[c] * invn;
  float var  = colsq[c] * invn - mean*mean;
  var = fmaxf(var, 0.f);
  float sc = gamma[c] * rsqrtf(var + EPS);
  ss[c] = sc;
  ss[DD + c] = beta[c] - mean*sc;
}

extern "C" void kernel_launch(void* const* d_in, const int* in_sizes, int n_in,
                              void* d_out, int out_size, void* d_ws, size_t ws_size,
                              hipStream_t stream) {
  const float* feat   = (const float*)d_in[0];
  const int*   src    = (const int*)d_in[1];
  const int*   dst    = (const int*)d_in[2];
  const float* Ws     = (const float*)d_in[3];
  const float* bs     = (const float*)d_in[4];
  const float* gammas = (const float*)d_in[5];
  const float* betas  = (const float*)d_in[6];
  float* out = (float*)d_out;

  int n  = in_sizes[0] / DD;   // 50000
  int ne = in_sizes[1];        // 800000

  char* p = (char*)d_ws;
  int* deg_out = (int*)p; p += (size_t)n*sizeof(int);
  int* deg_in  = (int*)p; p += (size_t)n*sizeof(int);
  int* rowptr  = (int*)p; p += (size_t)(n+1)*sizeof(int);
  int* cursor  = (int*)p; p += (size_t)n*sizeof(int);
  int* csr_src = (int*)p; p += (size_t)ne*sizeof(int);
  float* ns      = (float*)p; p += (size_t)n*sizeof(float);
  float* nd      = (float*)p; p += (size_t)n*sizeof(float);
  float* colsum  = (float*)p; p += DD*sizeof(float);
  float* colsq   = (float*)p; p += DD*sizeof(float);
  float* scsh    = (float*)p; p += 2*DD*sizeof(float);
  p = (char*)(((uintptr_t)p + 255) & ~(uintptr_t)255);
  unsigned short* B0 = (unsigned short*)p; p += (size_t)n*DD*sizeof(unsigned short);

  // degrees + norms + CSR build (recomputed every call; ws is poisoned)
  hipMemsetAsync(deg_out, 0, 2*(size_t)n*sizeof(int), stream);   // deg_out,deg_in contiguous
  degree_kernel<<<(ne+255)/256, 256, 0, stream>>>(src, dst, deg_out, deg_in, ne);
  norm_kernel<<<(n+255)/256, 256, 0, stream>>>(deg_out, deg_in, ns, nd, n);
  scan_kernel<<<1, 1024, 0, stream>>>(deg_in, rowptr, n);
  hipMemsetAsync(cursor, 0, (size_t)n*sizeof(int), stream);
  fill_kernel<<<(ne+255)/256, 256, 0, stream>>>(src, dst, rowptr, cursor, csr_src, ne);

  for (int L = 0; L < 3; L++){
    const float* hin = (L == 0) ? feat : out;
    gemm_kernel<<<(n+63)/64, 256, 0, stream>>>(hin, Ws + (size_t)L*DD*DD, ns, scsh, (L > 0) ? 1 : 0, B0, n);
    int do_stats = (L < 2) ? 1 : 0;
    if (do_stats) hipMemsetAsync(colsum, 0, 2*DD*sizeof(float), stream);  // colsum,colsq contiguous
    agg_kernel<<<2048, 256, 0, stream>>>(B0, rowptr, csr_src, nd, bs + (size_t)L*DD, out,
                                         colsum, colsq, do_stats, n);
    if (do_stats) bnfin_kernel<<<1, DD, 0, stream>>>(colsum, colsq, gammas + (size_t)L*DD,
                                                     betas + (size_t)L*DD, scsh, n);
  }
}